// Round 20
// baseline (610.821 us; speedup 1.0000x reference)
//
#include <hip/hip_runtime.h>
#include <hip/hip_cooperative_groups.h>

namespace cg = cooperative_groups;

typedef unsigned short u16;
typedef __attribute__((ext_vector_type(8))) short bf16x8;
typedef __attribute__((ext_vector_type(4))) float f32x4;
typedef __attribute__((ext_vector_type(8))) unsigned short u16x8;
typedef __attribute__((ext_vector_type(4))) unsigned short u16x4;

__device__ __forceinline__ u16 f2bf(float f){
  unsigned int u = __builtin_bit_cast(unsigned int, f);
  u += 0x7FFFu + ((u >> 16) & 1u);
  return (u16)(u >> 16);
}
__device__ __forceinline__ float bf2f(u16 h){
  unsigned int u = ((unsigned int)h) << 16;
  return __builtin_bit_cast(float, u);
}

__device__ __forceinline__ void load16(const u16* g, u16* s){
  __builtin_amdgcn_global_load_lds((const __attribute__((address_space(1))) unsigned int*)g,
                                   (__attribute__((address_space(3))) unsigned int*)s,
                                   16, 0, 0);
}

// vectorized f32 -> bf16 (8 elems / thread, exact multiple)
__global__ __launch_bounds__(256) void conv_bf16(const float* __restrict__ src, u16* __restrict__ dst){
  size_t i = (size_t)blockIdx.x * 256 + threadIdx.x;
  const float4* s = (const float4*)src + i * 2;
  float4 v0 = s[0], v1 = s[1];
  u16x8 o = { f2bf(v0.x), f2bf(v0.y), f2bf(v0.z), f2bf(v0.w),
              f2bf(v1.x), f2bf(v1.y), f2bf(v1.z), f2bf(v1.w) };
  *(u16x8*)(dst + i * 8) = o;
}

// 64x64-tile bt-form bf16 MFMA gemm core (NS steps; M=N=512; blk -> (8,8,8)).
// 4 waves (2Mx2N), 2x2 16x16x32 frags, single-buffered LDS, __syncthreads
// staging, 4-slot XOR swizzle (both-sides involution). Verbatim gemm_ns body.
template<int EPI>
__device__ __forceinline__ void ns_core(const u16* __restrict__ A, const u16* __restrict__ B,
                                        void* __restrict__ Cout, void* __restrict__ aux,
                                        void* __restrict__ aux2, int K,
                                        int blk, int t, char* As, char* Bs){
  const int bz = blk >> 6;
  const int m0 = ((blk >> 3) & 7) << 6;
  const int n0 = (blk & 7) << 6;
  const char* Ab = (const char*)(A + (size_t)bz * 512 * K);
  const char* Bb = (const char*)(B + (size_t)bz * 512 * K);
  const int w = t >> 6, l = t & 63;
  const int wm = w >> 1, wn = w & 1;
  const size_t Kb = (size_t)K << 1;
  const int sR = t >> 2;
  const int sK = ((t ^ (t >> 2)) & 3) << 4;
  const int kq = (((l >> 4) ^ l) & 3) << 4;
  const int aRd = ((wm << 5) + (l & 15)) * 64 + kq;
  const int bRd = ((wn << 5) + (l & 15)) * 64 + kq;
  f32x4 acc[2][2] = {};
  for (int k0 = 0; k0 < K; k0 += 32){
    const size_t kb = (size_t)k0 << 1;
    load16((const u16*)(Ab + (size_t)(m0 + sR) * Kb + kb + sK), (u16*)(As + t * 16));
    load16((const u16*)(Bb + (size_t)(n0 + sR) * Kb + kb + sK), (u16*)(Bs + t * 16));
    __syncthreads();
    bf16x8 aF[2], bF[2];
#pragma unroll
    for (int mf = 0; mf < 2; ++mf) aF[mf] = *(const bf16x8*)(As + aRd + (mf << 10));
#pragma unroll
    for (int nf = 0; nf < 2; ++nf) bF[nf] = *(const bf16x8*)(Bs + bRd + (nf << 10));
#pragma unroll
    for (int mf = 0; mf < 2; ++mf)
#pragma unroll
      for (int nf = 0; nf < 2; ++nf)
        acc[mf][nf] = __builtin_amdgcn_mfma_f32_16x16x32_bf16(aF[mf], bF[nf], acc[mf][nf], 0, 0, 0);
    __syncthreads();
  }
#pragma unroll
  for (int mf = 0; mf < 2; ++mf){
#pragma unroll
    for (int nf = 0; nf < 2; ++nf){
      const int col = n0 + (wn << 5) + (nf << 4) + (l & 15);
#pragma unroll
      for (int q = 0; q < 4; ++q){
        const int row = m0 + (wm << 5) + (mf << 4) + ((l >> 4) << 2) + q;
        float v = acc[mf][nf][q];
        size_t gi = ((size_t)bz * 512 + row) * 512 + col;
        size_t g2 = (((size_t)bz * 512 + row) << 10) + col;
        if (EPI == 2){
          ((u16*)Cout)[gi] = f2bf(v);
        } else if (EPI == 3){
          ((u16*)Cout)[gi] = f2bf((row == col ? 2.0f : 0.0f) - v);
        } else if (EPI == 9){
          ((u16*)Cout)[gi] = f2bf(v - (row == col ? 1.0f : 0.0f));
        } else {  // EPI 11
          float p = v + (row == col ? 1.000002f : 0.0f);
          u16 ph = f2bf(p);
          ((u16*)Cout)[g2] = ph;
          ((u16*)Cout)[g2 + 512] = f2bf(p - bf2f(ph));
          const float beta = 0.8264463f;
          u16 x1 = f2bf((row == col ? 2.0f * beta : 0.0f) - beta * beta * p);
          ((u16*)aux)[gi] = x1;
          ((u16*)aux2)[g2] = x1;
          ((u16*)aux2)[g2 + 512] = x1;
        }
      }
    }
  }
}

// ONE cooperative kernel: prep (build_s + W-transpose) + 4 NS gemms.
// [R16 retry: R16's failure (absmax 17.109) was BIT-IDENTICAL to R17's pure
//  layout bug (Wt clobbered by NS temps) — the cooperative launch itself was
//  never shown to fail. This version uses the R18-proven layout: Wt@[64,96)
//  disjoint from NS temps [0,36) for its whole lifetime.]
// 512 blocks x 256 thr = 2/CU co-resident; grid.sync() (device-scope fence)
// between dependent phases. All compute bodies verbatim from proven kernels.
__global__ __launch_bounds__(256) void ns_coop(const float* __restrict__ R, const float* __restrict__ W,
                                               u16* __restrict__ Sbf, u16* __restrict__ Dbf,
                                               u16* __restrict__ Wt, u16* __restrict__ Phl,
                                               u16* __restrict__ X1, u16* __restrict__ X1d,
                                               u16* __restrict__ Ybf, u16* __restrict__ X2,
                                               u16* __restrict__ G){
  cg::grid_group grid = cg::this_grid();
  __shared__ __align__(16) char As[4096];
  __shared__ __align__(16) char Bs[4096];
  __shared__ float tileT[32][33];
  const int blk = blockIdx.x;    // 0..511
  const int t = threadIdx.x;

  // Phase 1a: build_s over 2^21 elements (16 iters of 512x256)
#pragma unroll 1
  for (int it = 0; it < 16; ++it){
    int idx = (it * 512 + blk) * 256 + t;
    int b = idx >> 18;
    int i = (idx >> 9) & 511;
    int j = idx & 511;
    float a  = R[idx];
    float at = R[(b << 18) + (j << 9) + i];
    float s = 0.5f * (a - at);
    Sbf[idx] = f2bf(s);
    Dbf[idx] = f2bf((i == j ? 2.000003f : 0.0f) - 2.000001f * s);
  }
  // Phase 1b: W-transpose over 16384 32x32 tiles (32 iters)
#pragma unroll 1
  for (int it = 0; it < 32; ++it){
    int flat = it * 512 + blk;
    const int fx = flat & 127, fy = (flat >> 7) & 15, fz = flat >> 11;
    const int i0 = fx << 5, j0 = fy << 5;
    const int r = t >> 3, c = (t & 7) << 2;
    float4 v = *(const float4*)&W[(size_t)((fz << 9) + j0 + r) * 4096 + i0 + c];
    tileT[r][c+0] = v.x; tileT[r][c+1] = v.y; tileT[r][c+2] = v.z; tileT[r][c+3] = v.w;
    __syncthreads();
    u16x4 o = { f2bf(tileT[c+0][r]), f2bf(tileT[c+1][r]), f2bf(tileT[c+2][r]), f2bf(tileT[c+3][r]) };
    *(u16x4*)&Wt[((size_t)fz << 21) + (size_t)(i0 + r) * 512 + j0 + c] = o;
    __syncthreads();
  }
  grid.sync();
  // Phase 2: P = c^2 I + S S^T ; split epilogue -> Phl, X1, X1d
  ns_core<11>(Sbf, Sbf, Phl, X1, X1d, 512, blk, t, As, Bs);
  grid.sync();
  // Phase 3: Y = 2I - (Ph+Pl) X1  (K=1024)
  ns_core<3>(Phl, X1d, Ybf, nullptr, nullptr, 1024, blk, t, As, Bs);
  grid.sync();
  // Phase 4: X2 = X1 Y
  ns_core<2>(X1, Ybf, X2, nullptr, nullptr, 512, blk, t, As, Bs);
  grid.sync();
  // Phase 5: G = D X2 - I
  ns_core<9>(Dbf, X2, G, nullptr, nullptr, 512, blk, t, As, Bs);
}

// 256x256-tile bt-form bf16 MFMA gemm — ROUND-18 8-WAVE VERSION VERBATIM
// (replay-stable, 219.8 us @ MfmaUtil 57.3%). Structure plateau established:
// 4w/1-per-SIMD=33% (R10), 8w/2-per-SIMD=57% (R9/18), 16w/4-per-SIMD=55%
// (R19) — the ~57% is barrier-lockstep-structural, not TLP-limited; faithful
// 4-phase (R5) was 51%. EPI 0: f32 out = acc + aux[col]; EPI 2: bf16 C = acc.
template<int EPI>
__global__ __launch_bounds__(512, 2) void gemm256(const u16* __restrict__ A, const u16* __restrict__ B,
                                                  void* __restrict__ Cout, const float* __restrict__ aux,
                                                  int M, int N, int K){
  __shared__ __align__(16) char lds[131072];
  const int bz = blockIdx.z;
  const char* Ab = (const char*)(A + (size_t)bz * M * K);
  const char* Bb = (const char*)(B + (size_t)bz * N * K);
  const int NB = N >> 8;
  const int nwg = gridDim.x;
  const int bid = blockIdx.x;
  const int swzb = (bid & 7) * (nwg >> 3) + (bid >> 3);   // nwg % 8 == 0
  const int m0 = (swzb / NB) << 8;
  const int n0 = (swzb % NB) << 8;
  const int tid = threadIdx.x;
  const int w = tid >> 6, l = tid & 63;
  const int wm = w >> 2, wn = w & 3;
  const size_t Kb = (size_t)K << 1;
  const int NT = K >> 6;
  const int sRow = tid >> 3;
  const int sCol = ((tid & 7) << 4) ^ ((sRow & 7) << 4);
  const int sDst = tid << 4;
  const char* aS = Ab + (size_t)(m0 + sRow) * Kb + sCol;
  const char* bS = Bb + (size_t)(n0 + sRow) * Kb + sCol;
  const int lrow = (l & 15) << 7;
  const int kq0 = (((l >> 4) << 4)) ^ ((l & 7) << 4);
  const int aOff = (wm << 14) + lrow;
  const int bOff = 32768 + ((wn >> 1) << 14) + ((wn & 1) << 13) + lrow;

#define STAGE_H(isB, h, tt) { \
    const int _lo = (((tt) & 1) << 16) + ((isB) << 15) + ((h) << 14); \
    const char* _s = ((isB) ? bS : aS) + ((size_t)((h) << 7)) * Kb + ((size_t)(tt) << 7); \
    load16((const u16*)_s, (u16*)(lds + _lo + sDst)); \
    load16((const u16*)(_s + (Kb << 6)), (u16*)(lds + _lo + 8192 + sDst)); }

#define RD_A(bufb, UQ) \
  _Pragma("unroll") for (int i2 = 0; i2 < 4; ++i2){ \
    aF[i2][0] = *(const bf16x8*)(lds + (bufb) + aOff + ((UQ) << 13) + (i2 << 11) + kq0); \
    aF[i2][1] = *(const bf16x8*)(lds + (bufb) + aOff + ((UQ) << 13) + (i2 << 11) + (kq0 ^ 64)); }

#define RD_B(bufb, VQ) \
  _Pragma("unroll") for (int j2 = 0; j2 < 2; ++j2){ \
    bF[VQ][j2][0] = *(const bf16x8*)(lds + (bufb) + bOff + ((VQ) << 12) + (j2 << 11) + kq0); \
    bF[VQ][j2][1] = *(const bf16x8*)(lds + (bufb) + bOff + ((VQ) << 12) + (j2 << 11) + (kq0 ^ 64)); }

#define MFMA16(UQ, VQ) \
    _Pragma("unroll") for (int i2 = 0; i2 < 4; ++i2) \
      _Pragma("unroll") for (int j2 = 0; j2 < 2; ++j2){ \
        acc[(UQ)*4+i2][(VQ)*2+j2] = __builtin_amdgcn_mfma_f32_16x16x32_bf16(aF[i2][0], bF[VQ][j2][0], acc[(UQ)*4+i2][(VQ)*2+j2], 0, 0, 0); \
        acc[(UQ)*4+i2][(VQ)*2+j2] = __builtin_amdgcn_mfma_f32_16x16x32_bf16(aF[i2][1], bF[VQ][j2][1], acc[(UQ)*4+i2][(VQ)*2+j2], 0, 0, 0); }

#define BAR asm volatile("s_barrier" ::: "memory");
#define VM0 asm volatile("s_waitcnt vmcnt(0)" ::: "memory");

  bf16x8 aF[4][2], bF[2][2][2];
  f32x4 acc[8][4] = {};

  STAGE_H(0,0,0) STAGE_H(1,0,0) STAGE_H(0,1,0) STAGE_H(1,1,0)
  VM0 BAR

#define KTILE(t, bufb) { \
    RD_A(bufb, 0) RD_B(bufb, 0) \
    if ((t) + 1 < NT) { STAGE_H(0,0,(t)+1) STAGE_H(1,0,(t)+1) } \
    MFMA16(0,0) \
    RD_B(bufb, 1) \
    if ((t) + 1 < NT) { STAGE_H(0,1,(t)+1) STAGE_H(1,1,(t)+1) } \
    MFMA16(0,1) \
    RD_A(bufb, 1) \
    MFMA16(1,1) \
    MFMA16(1,0) \
    __builtin_amdgcn_sched_barrier(0); \
    VM0 BAR }

#pragma unroll 1
  for (int tp = 0; tp < NT; tp += 2){
    KTILE(tp, 0)
    KTILE(tp+1, 65536)
  }
#undef KTILE

#pragma unroll
  for (int mf = 0; mf < 8; ++mf){
#pragma unroll
    for (int nf = 0; nf < 4; ++nf){
      const int col = n0 + (wn << 6) + (nf << 4) + (l & 15);
#pragma unroll
      for (int q = 0; q < 4; ++q){
        const int row = m0 + (wm << 7) + (mf << 4) + ((l >> 4) << 2) + q;
        float v = acc[mf][nf][q];
        if (EPI == 0){
          ((float*)Cout)[(size_t)row * N + col] = v + aux[col];
        } else {
          ((u16*)Cout)[((size_t)bz * M + row) * N + col] = f2bf(v);
        }
      }
    }
  }
#undef STAGE_H
#undef RD_A
#undef RD_B
#undef MFMA16
#undef BAR
#undef VM0
}

extern "C" void kernel_launch(void* const* d_in, const int* in_sizes, int n_in,
                              void* d_out, int out_size, void* d_ws, size_t ws_size,
                              hipStream_t stream){
  const float* W    = (const float*)d_in[0];
  const float* bias = (const float*)d_in[1];
  const float* x    = (const float*)d_in[2];
  const float* R    = (const float*)d_in[3];
  (void)in_sizes; (void)n_in; (void)out_size; (void)ws_size;

  char* ws = (char*)d_ws;
  const size_t MiB = (size_t)1 << 20;
  // R18-proven lifetime-audited layout (max extent 100 MiB):
  //   coop     : writes Sbf[0,4) Dbf[4,8) Wt[64,96), NS temps within [0,36)
  //   filt gemm: reads G[0,4)+Wt[64,96), writes filt[4,36) (NS temps dead)
  //   conv     : writes xbf[36,100) (clobbers only dead X1d/Wt)
  //   main gemm: reads xbf[36,100) + filt[4,36)
  u16*   Sbf  = (u16*)(ws + 0 * MiB);
  u16*   Dbf  = (u16*)(ws + 4 * MiB);
  u16*   X1   = (u16*)(ws + 8 * MiB);
  u16*   Ybf  = (u16*)(ws + 12 * MiB);
  u16*   X2   = (u16*)(ws + 16 * MiB);
  u16*   Phl  = (u16*)(ws + 20 * MiB);
  u16*   X1d  = (u16*)(ws + 28 * MiB);
  u16*   G    = Sbf;
  u16*   filt = (u16*)(ws + 4 * MiB);
  u16*   Wt   = (u16*)(ws + 64 * MiB);
  u16*   xbf  = (u16*)(ws + 36 * MiB);

  // Phase A (1 cooperative dispatch): prep + 4 NS gemms
  void* args[] = { (void*)&R, (void*)&W, (void*)&Sbf, (void*)&Dbf, (void*)&Wt,
                   (void*)&Phl, (void*)&X1, (void*)&X1d, (void*)&Ybf, (void*)&X2,
                   (void*)&G };
  hipLaunchCooperativeKernel((const void*)ns_coop, dim3(512), dim3(256), args, 0, stream);
  // Phase B: filt = G @ Wb (bf16)
  gemm256<2><<<dim3(32, 1, 8), 512, 0, stream>>>(G, Wt, (void*)filt, nullptr, 512, 4096, 512);
  // Phase C: x -> bf16
  conv_bf16<<<16384, 256, 0, stream>>>(x, xbf);
  // Phase D: out = x @ filt^T + bias
  gemm256<0><<<dim3(512, 1, 1), 512, 0, stream>>>(xbf, filt, d_out, bias, 8192, 4096, 4096);
}

// Round 21
// 346.318 us; speedup vs baseline: 1.7638x; 1.7638x over previous
//
#include <hip/hip_runtime.h>

typedef unsigned short u16;
typedef __attribute__((ext_vector_type(8))) short bf16x8;
typedef __attribute__((ext_vector_type(4))) float f32x4;
typedef __attribute__((ext_vector_type(8))) unsigned short u16x8;
typedef __attribute__((ext_vector_type(4))) unsigned short u16x4;

__device__ __forceinline__ u16 f2bf(float f){
  unsigned int u = __builtin_bit_cast(unsigned int, f);
  u += 0x7FFFu + ((u >> 16) & 1u);
  return (u16)(u >> 16);
}
__device__ __forceinline__ float bf2f(u16 h){
  unsigned int u = ((unsigned int)h) << 16;
  return __builtin_bit_cast(float, u);
}

__device__ __forceinline__ void load16(const u16* g, u16* s){
  __builtin_amdgcn_global_load_lds((const __attribute__((address_space(1))) unsigned int*)g,
                                   (__attribute__((address_space(3))) unsigned int*)s,
                                   16, 0, 0);
}

// Fused preamble (build_s + W-transpose; independent, disjoint outputs).
// [R20: cooperative fusion of the NS chain measured at +265 us net —
//  grid.sync() costs ~60-70 us each on a 512-block grid. Separate dispatches
//  with ~4 us gaps are the right configuration.]
__global__ __launch_bounds__(256) void prep_sw(const float* __restrict__ R, const float* __restrict__ W,
                                               u16* __restrict__ Sbf, u16* __restrict__ Dbf,
                                               u16* __restrict__ Wt){
  const int blk = blockIdx.x;
  const int t = threadIdx.x;
  if (blk < 8192){
    int idx = blk * 256 + t;
    int b = idx >> 18;
    int i = (idx >> 9) & 511;
    int j = idx & 511;
    float a  = R[idx];
    float at = R[(b << 18) + (j << 9) + i];
    float s = 0.5f * (a - at);
    Sbf[idx] = f2bf(s);
    Dbf[idx] = f2bf((i == j ? 2.000003f : 0.0f) - 2.000001f * s);
  }
  __shared__ float tile[32][33];
  const int fx = blk & 127, fy = (blk >> 7) & 15, fz = blk >> 11;
  const int i0 = fx << 5, j0 = fy << 5;
  const int r = t >> 3, c = (t & 7) << 2;
  float4 v = *(const float4*)&W[(size_t)((fz << 9) + j0 + r) * 4096 + i0 + c];
  tile[r][c+0] = v.x; tile[r][c+1] = v.y; tile[r][c+2] = v.z; tile[r][c+3] = v.w;
  __syncthreads();
  u16x4 o = { f2bf(tile[c+0][r]), f2bf(tile[c+1][r]), f2bf(tile[c+2][r]), f2bf(tile[c+3][r]) };
  *(u16x4*)&Wt[((size_t)fz << 21) + (size_t)(i0 + r) * 512 + j0 + c] = o;
}

// vectorized f32 -> bf16 (8 elems / thread, exact multiple)
__global__ __launch_bounds__(256) void conv_bf16(const float* __restrict__ src, u16* __restrict__ dst){
  size_t i = (size_t)blockIdx.x * 256 + threadIdx.x;
  const float4* s = (const float4*)src + i * 2;
  float4 v0 = s[0], v1 = s[1];
  u16x8 o = { f2bf(v0.x), f2bf(v0.y), f2bf(v0.z), f2bf(v0.w),
              f2bf(v1.x), f2bf(v1.y), f2bf(v1.z), f2bf(v1.w) };
  *(u16x8*)(dst + i * 8) = o;
}

// 64x64-tile bt-form bf16 MFMA gemm for the small NS steps: grid (N/64, M/64, 8)
// = 512 blocks (2 blocks/CU). 4 waves (2Mx2N), each 32x32 (2x2 16x16x32 frags).
// Single-buffered LDS, __syncthreads staging (deterministic class), 4-slot XOR
// swizzle: LDS[r][slot] = G[r][slot ^ (r&3)], read slot ((l>>4)^l)&3.
// EPI 2:  bf16 C = acc
// EPI 3:  bf16 C = 2*diag - acc
// EPI 9:  bf16 C = acc - diag
// EPI 11: p = acc + c^2*diag (f32): Cout(width1024)=[bf16(p)|bf16(p-ph)];
//         x1 = bf16(2b*diag - b^2*p) -> aux (width 512) and aux2 (width 1024, dup)
template<int EPI>
__global__ __launch_bounds__(256) void gemm_ns(const u16* __restrict__ A, const u16* __restrict__ B,
                                               void* __restrict__ Cout, void* __restrict__ aux,
                                               void* __restrict__ aux2,
                                               int M, int N, int K){
  const int bz = blockIdx.z;
  const char* Ab = (const char*)(A + (size_t)bz * M * K);
  const char* Bb = (const char*)(B + (size_t)bz * N * K);
  const int m0 = blockIdx.y << 6, n0 = blockIdx.x << 6;
  __shared__ __align__(16) char As[4096];
  __shared__ __align__(16) char Bs[4096];
  const int t = threadIdx.x;
  const int w = t >> 6, l = t & 63;
  const int wm = w >> 1, wn = w & 1;
  const size_t Kb = (size_t)K << 1;
  const int sR = t >> 2;
  const int sK = ((t ^ (t >> 2)) & 3) << 4;
  const int kq = (((l >> 4) ^ l) & 3) << 4;
  const int aRd = ((wm << 5) + (l & 15)) * 64 + kq;
  const int bRd = ((wn << 5) + (l & 15)) * 64 + kq;
  f32x4 acc[2][2] = {};
  for (int k0 = 0; k0 < K; k0 += 32){
    const size_t kb = (size_t)k0 << 1;
    load16((const u16*)(Ab + (size_t)(m0 + sR) * Kb + kb + sK), (u16*)(As + t * 16));
    load16((const u16*)(Bb + (size_t)(n0 + sR) * Kb + kb + sK), (u16*)(Bs + t * 16));
    __syncthreads();
    bf16x8 aF[2], bF[2];
#pragma unroll
    for (int mf = 0; mf < 2; ++mf) aF[mf] = *(const bf16x8*)(As + aRd + (mf << 10));
#pragma unroll
    for (int nf = 0; nf < 2; ++nf) bF[nf] = *(const bf16x8*)(Bs + bRd + (nf << 10));
#pragma unroll
    for (int mf = 0; mf < 2; ++mf)
#pragma unroll
      for (int nf = 0; nf < 2; ++nf)
        acc[mf][nf] = __builtin_amdgcn_mfma_f32_16x16x32_bf16(aF[mf], bF[nf], acc[mf][nf], 0, 0, 0);
    __syncthreads();
  }
#pragma unroll
  for (int mf = 0; mf < 2; ++mf){
#pragma unroll
    for (int nf = 0; nf < 2; ++nf){
      const int col = n0 + (wn << 5) + (nf << 4) + (l & 15);
#pragma unroll
      for (int q = 0; q < 4; ++q){
        const int row = m0 + (wm << 5) + (mf << 4) + ((l >> 4) << 2) + q;
        float v = acc[mf][nf][q];
        size_t gi = ((size_t)bz * M + row) * N + col;
        size_t g2 = (((size_t)bz * M + row) << 10) + col;
        if (EPI == 2){
          ((u16*)Cout)[gi] = f2bf(v);
        } else if (EPI == 3){
          ((u16*)Cout)[gi] = f2bf((row == col ? 2.0f : 0.0f) - v);
        } else if (EPI == 9){
          ((u16*)Cout)[gi] = f2bf(v - (row == col ? 1.0f : 0.0f));
        } else {  // EPI 11
          float p = v + (row == col ? 1.000002f : 0.0f);
          u16 ph = f2bf(p);
          ((u16*)Cout)[g2] = ph;
          ((u16*)Cout)[g2 + 512] = f2bf(p - bf2f(ph));
          const float beta = 0.8264463f;
          u16 x1 = f2bf((row == col ? 2.0f * beta : 0.0f) - beta * beta * p);
          ((u16*)aux)[gi] = x1;
          ((u16*)aux2)[g2] = x1;
          ((u16*)aux2)[g2 + 512] = x1;
        }
      }
    }
  }
}

// 256x256-tile bt-form bf16 MFMA gemm — ROUND-9/18 8-WAVE VERSION VERBATIM
// (replay-stable, 219.8 us @ MfmaUtil 57.3%). Structure plateau established
// empirically: 4w/1-per-SIMD=33% (R10), 8w/2-per-SIMD=57% (R9/18),
// 16w/4-per-SIMD=55% (R19), 4-phase-interleave=51% (R5) — ~57% is
// barrier-lockstep-structural. Sync: stage ONLY tile t+1 into buffer (t+1)&1,
// one vmcnt(0)+s_barrier per K-tile, LDS XOR-swizzle byte^=((row&7)<<4)
// both-sides. EPI 0: f32 out = acc + aux[col] (bias) ; EPI 2: bf16 C = acc
template<int EPI>
__global__ __launch_bounds__(512, 2) void gemm256(const u16* __restrict__ A, const u16* __restrict__ B,
                                                  void* __restrict__ Cout, const float* __restrict__ aux,
                                                  int M, int N, int K){
  __shared__ __align__(16) char lds[131072];
  const int bz = blockIdx.z;
  const char* Ab = (const char*)(A + (size_t)bz * M * K);
  const char* Bb = (const char*)(B + (size_t)bz * N * K);
  const int NB = N >> 8;
  const int nwg = gridDim.x;
  const int bid = blockIdx.x;
  const int swzb = (bid & 7) * (nwg >> 3) + (bid >> 3);   // nwg % 8 == 0
  const int m0 = (swzb / NB) << 8;
  const int n0 = (swzb % NB) << 8;
  const int tid = threadIdx.x;
  const int w = tid >> 6, l = tid & 63;
  const int wm = w >> 2, wn = w & 3;
  const size_t Kb = (size_t)K << 1;
  const int NT = K >> 6;
  const int sRow = tid >> 3;
  const int sCol = ((tid & 7) << 4) ^ ((sRow & 7) << 4);
  const int sDst = tid << 4;
  const char* aS = Ab + (size_t)(m0 + sRow) * Kb + sCol;
  const char* bS = Bb + (size_t)(n0 + sRow) * Kb + sCol;
  const int lrow = (l & 15) << 7;
  const int kq0 = (((l >> 4) << 4)) ^ ((l & 7) << 4);
  const int aOff = (wm << 14) + lrow;
  const int bOff = 32768 + ((wn >> 1) << 14) + ((wn & 1) << 13) + lrow;

#define STAGE_H(isB, h, tt) { \
    const int _lo = (((tt) & 1) << 16) + ((isB) << 15) + ((h) << 14); \
    const char* _s = ((isB) ? bS : aS) + ((size_t)((h) << 7)) * Kb + ((size_t)(tt) << 7); \
    load16((const u16*)_s, (u16*)(lds + _lo + sDst)); \
    load16((const u16*)(_s + (Kb << 6)), (u16*)(lds + _lo + 8192 + sDst)); }

#define RD_A(bufb, UQ) \
  _Pragma("unroll") for (int i2 = 0; i2 < 4; ++i2){ \
    aF[i2][0] = *(const bf16x8*)(lds + (bufb) + aOff + ((UQ) << 13) + (i2 << 11) + kq0); \
    aF[i2][1] = *(const bf16x8*)(lds + (bufb) + aOff + ((UQ) << 13) + (i2 << 11) + (kq0 ^ 64)); }

#define RD_B(bufb, VQ) \
  _Pragma("unroll") for (int j2 = 0; j2 < 2; ++j2){ \
    bF[VQ][j2][0] = *(const bf16x8*)(lds + (bufb) + bOff + ((VQ) << 12) + (j2 << 11) + kq0); \
    bF[VQ][j2][1] = *(const bf16x8*)(lds + (bufb) + bOff + ((VQ) << 12) + (j2 << 11) + (kq0 ^ 64)); }

#define MFMA16(UQ, VQ) \
    _Pragma("unroll") for (int i2 = 0; i2 < 4; ++i2) \
      _Pragma("unroll") for (int j2 = 0; j2 < 2; ++j2){ \
        acc[(UQ)*4+i2][(VQ)*2+j2] = __builtin_amdgcn_mfma_f32_16x16x32_bf16(aF[i2][0], bF[VQ][j2][0], acc[(UQ)*4+i2][(VQ)*2+j2], 0, 0, 0); \
        acc[(UQ)*4+i2][(VQ)*2+j2] = __builtin_amdgcn_mfma_f32_16x16x32_bf16(aF[i2][1], bF[VQ][j2][1], acc[(UQ)*4+i2][(VQ)*2+j2], 0, 0, 0); }

#define BAR asm volatile("s_barrier" ::: "memory");
#define VM0 asm volatile("s_waitcnt vmcnt(0)" ::: "memory");

  bf16x8 aF[4][2], bF[2][2][2];
  f32x4 acc[8][4] = {};

  // prologue: stage tile 0 fully into buf 0
  STAGE_H(0,0,0) STAGE_H(1,0,0) STAGE_H(0,1,0) STAGE_H(1,1,0)
  VM0 BAR

  // one barrier per K-tile; stages target only the non-read buffer
#define KTILE(t, bufb) { \
    RD_A(bufb, 0) RD_B(bufb, 0) \
    if ((t) + 1 < NT) { STAGE_H(0,0,(t)+1) STAGE_H(1,0,(t)+1) } \
    MFMA16(0,0) \
    RD_B(bufb, 1) \
    if ((t) + 1 < NT) { STAGE_H(0,1,(t)+1) STAGE_H(1,1,(t)+1) } \
    MFMA16(0,1) \
    RD_A(bufb, 1) \
    MFMA16(1,1) \
    MFMA16(1,0) \
    __builtin_amdgcn_sched_barrier(0); \
    VM0 BAR }

#pragma unroll 1
  for (int tp = 0; tp < NT; tp += 2){
    KTILE(tp, 0)
    KTILE(tp+1, 65536)
  }
#undef KTILE

#pragma unroll
  for (int mf = 0; mf < 8; ++mf){
#pragma unroll
    for (int nf = 0; nf < 4; ++nf){
      const int col = n0 + (wn << 6) + (nf << 4) + (l & 15);
#pragma unroll
      for (int q = 0; q < 4; ++q){
        const int row = m0 + (wm << 7) + (mf << 4) + ((l >> 4) << 2) + q;
        float v = acc[mf][nf][q];
        if (EPI == 0){
          ((float*)Cout)[(size_t)row * N + col] = v + aux[col];
        } else {
          ((u16*)Cout)[((size_t)bz * M + row) * N + col] = f2bf(v);
        }
      }
    }
  }
#undef STAGE_H
#undef RD_A
#undef RD_B
#undef MFMA16
#undef BAR
#undef VM0
}

extern "C" void kernel_launch(void* const* d_in, const int* in_sizes, int n_in,
                              void* d_out, int out_size, void* d_ws, size_t ws_size,
                              hipStream_t stream){
  const float* W    = (const float*)d_in[0];
  const float* bias = (const float*)d_in[1];
  const float* x    = (const float*)d_in[2];
  const float* R    = (const float*)d_in[3];
  (void)in_sizes; (void)n_in; (void)out_size; (void)ws_size;

  char* ws = (char*)d_ws;
  const size_t MiB = (size_t)1 << 20;
  // R18-proven lifetime-audited layout (max extent 100 MiB):
  //   phase 1  : writes Sbf[0,4) Dbf[4,8) Wt[64,96)
  //   phase 2-5: NS temps all within [0,36); Wt untouched
  //   phase 6  : reads G[0,4)+Wt[64,96), writes filt[4,36) (NS temps dead)
  //   phase 7  : writes xbf[36,100) (clobbers only dead X1d/Wt)
  //   phase 8  : reads xbf[36,100) + filt[4,36)
  u16*   Sbf  = (u16*)(ws + 0 * MiB);
  u16*   Dbf  = (u16*)(ws + 4 * MiB);
  u16*   X1   = (u16*)(ws + 8 * MiB);
  u16*   Ybf  = (u16*)(ws + 12 * MiB);
  u16*   X2   = (u16*)(ws + 16 * MiB);
  u16*   Phl  = (u16*)(ws + 20 * MiB);
  u16*   X1d  = (u16*)(ws + 28 * MiB);
  u16*   G    = Sbf;
  u16*   filt = (u16*)(ws + 4 * MiB);
  u16*   Wt   = (u16*)(ws + 64 * MiB);
  u16*   xbf  = (u16*)(ws + 36 * MiB);

  const dim3 gNS(8, 8, 8);

  // Phase 1: fused build_s + W-transpose
  prep_sw<<<16384, 256, 0, stream>>>(R, W, Sbf, Dbf, Wt);
  // Phase 2: P = c^2 I + S S^T ; fused epilogue emits Phl=[Ph|Pl], X1, X1d
  gemm_ns<11><<<gNS, 256, 0, stream>>>(Sbf, Sbf, Phl, X1, X1d, 512, 512, 512);
  // Phase 3: Y = 2I - (Ph+Pl) X1   (K=1024, full-precision P)
  gemm_ns<3><<<gNS, 256, 0, stream>>>(Phl, X1d, Ybf, nullptr, nullptr, 512, 512, 1024);
  // Phase 4: X2 = X1 Y
  gemm_ns<2><<<gNS, 256, 0, stream>>>(X1, Ybf, X2, nullptr, nullptr, 512, 512, 512);
  // Phase 5: G = Q = D X2 - I
  gemm_ns<9><<<gNS, 256, 0, stream>>>(Dbf, X2, G, nullptr, nullptr, 512, 512, 512);
  // Phase 6: filt = G @ Wb (bf16)
  gemm256<2><<<dim3(32, 1, 8), 512, 0, stream>>>(G, Wt, (void*)filt, nullptr, 512, 4096, 512);
  // Phase 7: x -> bf16
  conv_bf16<<<16384, 256, 0, stream>>>(x, xbf);
  // Phase 8: out = x @ filt^T + bias
  gemm256<0><<<dim3(512, 1, 1), 512, 0, stream>>>(xbf, filt, d_out, bias, 8192, 4096, 4096);
}